// Round 5
// baseline (214.962 us; speedup 1.0000x reference)
//
#include <hip/hip_runtime.h>

// Reference collapses: softmax over a size-1 key axis == 1.0, so
// out[bn,t,:] = padded[bn,t,:] + (masked_mean_t(padded[bn]) @ Wv + bv).
// q/k/rope/positions/sum_token are dead code.
//
// R9: wave-autonomous single kernel, ONE barrier.  Post-mortems R5/R7/R8:
// register residency is unwinnable (VGPR_Count=64 every time -> compiler
// spills/rematerializes around the pins), and the 12-wave lockstep phase
// structure left HBM idle during reduce/matvec (70us vs 24us HBM floor).
// New structure: block = 384 thr (6 waves) owns one bn; wave w owns an
// exclusive 16-float4 column slice; lane = (rg = lane>>4 row-group,
// colg = lane&15).
//   phase 1 (wave-local, no LDS): masked colsum + denom over rows rg+4j,
//           __shfl_xor(16,32) butterfly across row-groups.
//   -> write 96 summary float4 to LDS, __syncthreads (the ONLY barrier).
//   phase 2 (wave-local): matvec for own col4, e = rg+4j (LDS broadcast,
//           4 distinct banks per access -> conflict-free), butterfly, +bv.
//   phase 3 (wave-local): re-read own slice (L3-hot) + add + nt-store.
// After the barrier waves drift independently; 2 co-resident blocks/CU
// (VGPR ~50, LDS 1.5 KB) interleave load/matvec/store phases across the
// CU, keeping HBM and L2 pipes concurrently busy.

#define DM 384
#define TT 128
#define C4 96          // DM / 4
#define BN_TOT 512

typedef float f32x4 __attribute__((ext_vector_type(4)));

__device__ __forceinline__ void nt_store4(float4* p, const float4 v) {
    __builtin_nontemporal_store(*(const f32x4*)&v, (f32x4*)p);
}

__global__ __launch_bounds__(384) void fused_wave(
    const float* __restrict__ padded,
    const int*   __restrict__ masks,
    const float* __restrict__ Wv,
    const float* __restrict__ bv,
    float*       __restrict__ out)
{
    const int bn   = blockIdx.x;
    const int t    = threadIdx.x;
    const int lane = t & 63;
    const int wid  = t >> 6;          // wave 0..5
    const int colg = lane & 15;
    const int rg   = lane >> 4;       // row-group 0..3
    const int c4   = wid * 16 + colg; // this lane's float4 column 0..95

    __shared__ float summ_sh[DM];     // 1.5 KB

    const float4* __restrict__ p4 = (const float4*)padded + (size_t)bn * TT * C4;
    const int*    __restrict__ mk = masks + bn * TT;

    // ---- phase 1: masked colsum + denom over rows rg+4j (wave-local) ----
    float4 a0 = make_float4(0.f, 0.f, 0.f, 0.f);
    float4 a1 = make_float4(0.f, 0.f, 0.f, 0.f);
    float  ws0 = 0.f, ws1 = 0.f;
    #pragma unroll
    for (int j = 0; j < 16; ++j) {
        const int rA = rg + 8 * j;        // rows rg, rg+8, ...
        const int rB = rA + 4;            // rows rg+4, rg+12, ...
        const float wA = (float)mk[rA];   // 16-lane broadcast, L1-hot
        const float wB = (float)mk[rB];
        const float4 xA = p4[rA * C4 + c4];
        const float4 xB = p4[rB * C4 + c4];
        a0.x += xA.x * wA; a0.y += xA.y * wA; a0.z += xA.z * wA; a0.w += xA.w * wA;
        a1.x += xB.x * wB; a1.y += xB.y * wB; a1.z += xB.z * wB; a1.w += xB.w * wB;
        ws0 += wA; ws1 += wB;
    }
    a0.x += a1.x; a0.y += a1.y; a0.z += a1.z; a0.w += a1.w;
    ws0 += ws1;

    // butterfly across row-groups (lane bits 4,5)
    #pragma unroll
    for (int m = 16; m < 64; m <<= 1) {
        a0.x += __shfl_xor(a0.x, m, 64);
        a0.y += __shfl_xor(a0.y, m, 64);
        a0.z += __shfl_xor(a0.z, m, 64);
        a0.w += __shfl_xor(a0.w, m, 64);
        ws0  += __shfl_xor(ws0,  m, 64);
    }
    const float inv = 1.0f / fmaxf(ws0, 1e-6f);
    if (rg == 0) {
        float4 s;
        s.x = a0.x * inv; s.y = a0.y * inv; s.z = a0.z * inv; s.w = a0.w * inv;
        ((float4*)summ_sh)[c4] = s;
    }
    __syncthreads();                      // the ONLY barrier

    // ---- phase 2: matvec for own col4; e = rg+4j (wave-local) ----
    // LDS banks per access: {4j, 4j+1, 4j+2, 4j+3} -> 4 distinct, no conflict.
    float4 v = make_float4(0.f, 0.f, 0.f, 0.f);
    const float4* __restrict__ wv4 = (const float4*)Wv;
    #pragma unroll 8
    for (int j = 0; j < C4; ++j) {
        const int   e = rg + 4 * j;
        const float s = summ_sh[e];               // 16-lane LDS broadcast
        const float4 w = wv4[(size_t)e * C4 + c4]; // 256B/row-group, L2-hot
        v.x += s * w.x; v.y += s * w.y; v.z += s * w.z; v.w += s * w.w;
    }
    #pragma unroll
    for (int m = 16; m < 64; m <<= 1) {
        v.x += __shfl_xor(v.x, m, 64);
        v.y += __shfl_xor(v.y, m, 64);
        v.z += __shfl_xor(v.z, m, 64);
        v.w += __shfl_xor(v.w, m, 64);
    }
    const float4 b = ((const float4*)bv)[c4];
    v.x += b.x; v.y += b.y; v.z += b.z; v.w += b.w;

    // ---- phase 3: out = padded + v (re-read own slice, L3-hot) ----
    float4* __restrict__ o4 = (float4*)out + (size_t)bn * TT * C4;
    #pragma unroll
    for (int j = 0; j < 32; ++j) {
        const int r = rg + 4 * j;
        float4 x = p4[r * C4 + c4];
        x.x += v.x; x.y += v.y; x.z += v.z; x.w += v.w;
        nt_store4(&o4[r * C4 + c4], x);
    }
}

extern "C" void kernel_launch(void* const* d_in, const int* in_sizes, int n_in,
                              void* d_out, int out_size, void* d_ws, size_t ws_size,
                              hipStream_t stream) {
    const float* padded = (const float*)d_in[0];
    // d_in[1] sum_token, d_in[2] positions_3d, d_in[3..6] Wq/bq/Wk/bk: dead
    const float* Wv     = (const float*)d_in[7];
    const float* bv     = (const float*)d_in[8];
    const int*   masks  = (const int*)d_in[9];
    float* out = (float*)d_out;

    fused_wave<<<BN_TOT, 384, 0, stream>>>(padded, masks, Wv, bv, out);
}

// Round 6
// 214.465 us; speedup vs baseline: 1.0023x; 1.0023x over previous
//
#include <hip/hip_runtime.h>

// Reference collapses: softmax over a size-1 key axis == 1.0, so
// out[bn,t,:] = padded[bn,t,:] + (masked_mean_t(padded[bn]) @ Wv + bv).
// q/k/rope/positions/sum_token are dead code.
//
// R10: wave-autonomous + bn-pairing.  R9 post-mortem: FETCH doubled
// (54->99.7 MB) because the chip-wide 295 MB of Wv matvec traffic evicted
// each block's tile from L2/L3 between its phase-1 read and phase-3
// re-read (+46 MB HBM re-fetch = the 8.5us regression).  Fix:
//   - block = 768 thr (12 waves) owns bn pair; waves 0-5 run the full
//     pipeline for bn0, waves 6-11 for bn1, in parallel.  Wv traffic
//     halves (256 x 576 KB = 147 MB) and both groups sweep Wv rows in
//     the same order on the same CU -> L1/L2 line sharing.
//   - exactly 1 block/CU (256 blocks, 32/XCD - balanced), no rounds;
//     after the single barrier the two groups drift, overlapping one
//     group's stores with the other's matvec.
//   - kept from R9: per-wave column slices, __shfl_xor butterflies
//     (no LDS lockstep), ONE __syncthreads, nt stores for out,
//     normal (L3-allocating) loads for padded.
//   - register residency abandoned for good (R5/R7/R8: compiler always
//     rematerializes; VGPR_Count=64 every time).
// Prediction: FETCH back to ~55 MB, kernel ~55-63us.

#define DM 384
#define TT 128
#define C4 96          // DM / 4
#define NBLK 256       // 512 bn / 2 per block

typedef float f32x4 __attribute__((ext_vector_type(4)));

__device__ __forceinline__ void nt_store4(float4* p, const float4 v) {
    __builtin_nontemporal_store(*(const f32x4*)&v, (f32x4*)p);
}

__global__ __launch_bounds__(768) void fused_pair_wave(
    const float* __restrict__ padded,
    const int*   __restrict__ masks,
    const float* __restrict__ Wv,
    const float* __restrict__ bv,
    float*       __restrict__ out)
{
    const int t    = threadIdx.x;
    const int g    = t >= 384;            // bn-group 0/1 (waves 0-5 / 6-11)
    const int bn   = (blockIdx.x << 1) + g;
    const int lane = t & 63;
    const int wg   = ((t >= 384) ? (t - 384) : t) >> 6;  // wave-in-group 0..5
    const int colg = lane & 15;
    const int rg   = lane >> 4;           // row-group 0..3
    const int c4   = wg * 16 + colg;      // this lane's float4 column 0..95

    __shared__ float summ_sh[2][DM];      // 3 KB

    const float4* __restrict__ p4 = (const float4*)padded + (size_t)bn * TT * C4;
    const int*    __restrict__ mk = masks + bn * TT;

    // ---- phase 1: masked colsum + denom over rows rg+4k (wave-local) ----
    float4 a0 = make_float4(0.f, 0.f, 0.f, 0.f);
    float4 a1 = make_float4(0.f, 0.f, 0.f, 0.f);
    float  ws0 = 0.f, ws1 = 0.f;
    #pragma unroll
    for (int j = 0; j < 16; ++j) {
        const int rA = rg + 8 * j;        // rows rg, rg+8, ...
        const int rB = rA + 4;            // rows rg+4, rg+12, ...
        const float wA = (float)mk[rA];   // 16-lane broadcast, L1-hot
        const float wB = (float)mk[rB];
        const float4 xA = p4[rA * C4 + c4];
        const float4 xB = p4[rB * C4 + c4];
        a0.x += xA.x * wA; a0.y += xA.y * wA; a0.z += xA.z * wA; a0.w += xA.w * wA;
        a1.x += xB.x * wB; a1.y += xB.y * wB; a1.z += xB.z * wB; a1.w += xB.w * wB;
        ws0 += wA; ws1 += wB;
    }
    a0.x += a1.x; a0.y += a1.y; a0.z += a1.z; a0.w += a1.w;
    ws0 += ws1;

    // butterfly across row-groups (lane bits 4,5)
    #pragma unroll
    for (int m = 16; m < 64; m <<= 1) {
        a0.x += __shfl_xor(a0.x, m, 64);
        a0.y += __shfl_xor(a0.y, m, 64);
        a0.z += __shfl_xor(a0.z, m, 64);
        a0.w += __shfl_xor(a0.w, m, 64);
        ws0  += __shfl_xor(ws0,  m, 64);
    }
    const float inv = 1.0f / fmaxf(ws0, 1e-6f);
    if (rg == 0) {
        float4 s;
        s.x = a0.x * inv; s.y = a0.y * inv; s.z = a0.z * inv; s.w = a0.w * inv;
        ((float4*)summ_sh[g])[c4] = s;
    }
    __syncthreads();                      // the ONLY barrier

    // ---- phase 2: matvec for own col4; e = rg+4j (wave-local) ----
    // Both groups sweep e in the same order -> shared Wv lines on the CU.
    float4 v = make_float4(0.f, 0.f, 0.f, 0.f);
    const float4* __restrict__ wv4 = (const float4*)Wv;
    const float*  __restrict__ sm  = summ_sh[g];
    #pragma unroll 8
    for (int j = 0; j < C4; ++j) {
        const int   e = rg + 4 * j;
        const float s = sm[e];                     // 16-lane LDS broadcast
        const float4 w = wv4[(size_t)e * C4 + c4]; // coalesced, L2-hot
        v.x += s * w.x; v.y += s * w.y; v.z += s * w.z; v.w += s * w.w;
    }
    #pragma unroll
    for (int m = 16; m < 64; m <<= 1) {
        v.x += __shfl_xor(v.x, m, 64);
        v.y += __shfl_xor(v.y, m, 64);
        v.z += __shfl_xor(v.z, m, 64);
        v.w += __shfl_xor(v.w, m, 64);
    }
    const float4 b = ((const float4*)bv)[c4];
    v.x += b.x; v.y += b.y; v.z += b.z; v.w += b.w;

    // ---- phase 3: out = padded + v (re-read own slice, issued right
    //      after this group's matvec -> L2/L3-hot) ----
    float4* __restrict__ o4 = (float4*)out + (size_t)bn * TT * C4;
    #pragma unroll
    for (int j = 0; j < 32; ++j) {
        const int r = rg + 4 * j;
        float4 x = p4[r * C4 + c4];
        x.x += v.x; x.y += v.y; x.z += v.z; x.w += v.w;
        nt_store4(&o4[r * C4 + c4], x);
    }
}

extern "C" void kernel_launch(void* const* d_in, const int* in_sizes, int n_in,
                              void* d_out, int out_size, void* d_ws, size_t ws_size,
                              hipStream_t stream) {
    const float* padded = (const float*)d_in[0];
    // d_in[1] sum_token, d_in[2] positions_3d, d_in[3..6] Wq/bq/Wk/bk: dead
    const float* Wv     = (const float*)d_in[7];
    const float* bv     = (const float*)d_in[8];
    const int*   masks  = (const int*)d_in[9];
    float* out = (float*)d_out;

    fused_pair_wave<<<NBLK, 768, 0, stream>>>(padded, masks, Wv, bv, out);
}